// Round 2
// baseline (8411.723 us; speedup 1.0000x reference)
//
#include <hip/hip_runtime.h>
#include <hip/hip_fp16.h>

typedef _Float16 f16;
typedef _Float16 f16x8 __attribute__((ext_vector_type(8)));
typedef float    f32x4 __attribute__((ext_vector_type(4)));

__device__ __forceinline__ float sigm(float x) { return 1.f / (1.f + __expf(-x)); }
__device__ __forceinline__ float reluf(float x) { return x > 0.f ? x : 0.f; }

// ---------------- pack B for MFMA b-frag layout (validated in R1 via gemm_xw)
// dst[((c*KF+kf)*64+L)*8+j] = B[kf*32 + (L>>4)*8 + j][c*16 + (L&15)]
template <int KF>
__global__ void pack_bsw(const float* __restrict__ B, f16* __restrict__ dst, int N) {
  int id = blockIdx.x * 256 + threadIdx.x;
  int total = KF * 32 * N;
  if (id >= total) return;
  int j  = id & 7;
  int L  = (id >> 3) & 63;
  int r  = id >> 9;
  int kf = r & (KF - 1);
  int c  = r / KF;
  int k  = kf * 32 + ((L >> 4) * 8) + j;
  int n  = c * 16 + (L & 15);
  dst[id] = (f16)B[k * N + n];
}

// ---------------- xW GEMM: C[M][N] = gather(emb, tok)[M][K] @ B[K][N] + bias, f16 out
template <int K, int KF, int N, int NC>
__global__ __launch_bounds__(256) void gemm_xw(const int* __restrict__ tok,
                                               const float* __restrict__ emb,
                                               const f16* __restrict__ Bsw,
                                               const float* __restrict__ bias,
                                               f16* __restrict__ C) {
  __shared__ int tokLds[64];
  __shared__ f16x8 bLds[8 * 64];
  const int tid = threadIdx.x;
  const int blk = blockIdx.x;
  if (tid < 64) tokLds[tid] = tok[blk * 64 + tid];
  __syncthreads();
  const int wave = tid >> 6, lane = tid & 63;
  const int quad = lane >> 4, l16 = lane & 15;
  const int m0 = wave * 16;

  f16x8 a[KF];
  {
    const int row = m0 + l16;
    const float* arow = emb + (long)tokLds[row] * K + quad * 8;
#pragma unroll
    for (int kf = 0; kf < KF; kf++) {
      float4 v0 = *(const float4*)(arow + kf * 32);
      float4 v1 = *(const float4*)(arow + kf * 32 + 4);
      f16x8 tv;
      tv[0] = (f16)v0.x; tv[1] = (f16)v0.y; tv[2] = (f16)v0.z; tv[3] = (f16)v0.w;
      tv[4] = (f16)v1.x; tv[5] = (f16)v1.y; tv[6] = (f16)v1.z; tv[7] = (f16)v1.w;
      a[kf] = tv;
    }
  }
  const long crow = (long)(blk * 64 + m0) * N;
  const f16x8* Bfrag = (const f16x8*)Bsw;
  for (int c = 0; c < NC; c++) {
    for (int i = tid; i < KF * 64; i += 256) bLds[i] = Bfrag[c * KF * 64 + i];
    __syncthreads();
    f32x4 acc = {0.f, 0.f, 0.f, 0.f};
#pragma unroll
    for (int kf = 0; kf < KF; kf++)
      acc = __builtin_amdgcn_mfma_f32_16x16x32_f16(a[kf], bLds[kf * 64 + lane], acc, 0, 0, 0);
    const int col = c * 16 + l16;
    const float bc = bias[col];
#pragma unroll
    for (int r = 0; r < 4; r++)
      C[crow + (long)(quad * 4 + r) * N + col] = (f16)(acc[r] + bc);
    __syncthreads();
  }
}

// ---------------- MFMA recurrence: 16 seqs/block. blocks 0..7 paragraph, 8..15 title
struct RArgs {
  const f16 *xpW, *xtW;
  const f16 *U0f, *W1f, *U1f, *W2f, *U2f;   // paragraph b-frags
  const f16 *U0tf, *W1tf, *U1tf;            // title b-frags
  const float *pl1_b, *pl2_b, *tl1_b;
  const float *pd0W, *pd0b, *pd1W, *pd1b, *pd2W, *pd2b;
  const float *td0W, *td0b, *td1W, *td1b, *td2W, *td2b;
  float* feat;
};

#define H0S 264   // f16 row stride (256+8): 2-way max bank aliasing
#define H1S 136   // 128+8
#define H2S 72    // 64+8
#define ZS  516   // f32 row stride for zbuf

__global__ __launch_bounds__(1024) void recur2(RArgs A) {
  __shared__ float zb[16 * ZS];            // 33 KB (z scratch, MLP scratch)
  __shared__ f16 h0b[2][16 * H0S];         // para L0 h (double buffered)
  __shared__ f16 h1b[16 * H1S];            // para L1 h / title L0 h
  __shared__ f16 h2b[16 * H2S];            // para L2 h / title L1 h
  __shared__ float biasB[512];
  __shared__ float biasC[256];
  const int tid = threadIdx.x;
  const int w = tid >> 6, lane = tid & 63;
  const int quad = lane >> 4, l16 = lane & 15;
  const int blk = blockIdx.x;

  for (int i = tid; i < 16 * H0S; i += 1024) h0b[0][i] = (f16)0.f;
  for (int i = tid; i < 16 * H1S; i += 1024) h1b[i] = (f16)0.f;
  for (int i = tid; i < 16 * H2S; i += 1024) h2b[i] = (f16)0.f;

  const f16x8* U0v  = (const f16x8*)A.U0f;
  const f16x8* W1v  = (const f16x8*)A.W1f;
  const f16x8* U1v  = (const f16x8*)A.U1f;
  const f16x8* W2v  = (const f16x8*)A.W2f;
  const f16x8* U2v  = (const f16x8*)A.U2f;
  const f16x8* U0tv = (const f16x8*)A.U0tf;
  const f16x8* W1tv = (const f16x8*)A.W1tf;
  const f16x8* U1tv = (const f16x8*)A.U1tf;

  if (blk < 8) {
    // ================= paragraph: seqs s0..s0+15, 512 steps =================
    const int s0 = blk * 16;
    if (tid < 512) biasB[tid] = A.pl1_b[tid];
    if (tid < 256) biasC[tid] = A.pl2_b[tid];
    float c0[4] = {0.f, 0.f, 0.f, 0.f};
    float c1s[2] = {0.f, 0.f};
    float c2 = 0.f;
    const f16* xbase = A.xpW + (size_t)s0 * 512 * 1024;
    __syncthreads();

    for (int t = 0; t < 512; t++) {
      const f16* h0r = h0b[t & 1];
      f16*       h0w = h0b[(t + 1) & 1];
      // ---- phase A: layer0. wave w owns units 16w..16w+15 (tiles w,w+16,w+32,w+48 = i,f,g,o)
      float xv[4][4];
#pragma unroll
      for (int a = 0; a < 4; a++)
#pragma unroll
        for (int r = 0; r < 4; r++)
          xv[a][r] = (float)xbase[((size_t)(quad * 4 + r) * 512 + t) * 1024 + 16 * w + 256 * a + l16];
      f16x8 af[8];
#pragma unroll
      for (int kf = 0; kf < 8; kf++)
        af[kf] = *(const f16x8*)&h0r[l16 * H0S + kf * 32 + quad * 8];
      f32x4 acc[4];
#pragma unroll
      for (int a = 0; a < 4; a++) {
        const int nt = w + 16 * a;
        f32x4 z = {0.f, 0.f, 0.f, 0.f};
#pragma unroll
        for (int kf = 0; kf < 8; kf++)
          z = __builtin_amdgcn_mfma_f32_16x16x32_f16(af[kf], U0v[(nt * 8 + kf) * 64 + lane], z, 0, 0, 0);
        acc[a] = z;
      }
#pragma unroll
      for (int r = 0; r < 4; r++) {
        float ii = sigm(acc[0][r] + xv[0][r]);
        float ff = sigm(acc[1][r] + xv[1][r]);
        float gg = reluf(acc[2][r] + xv[2][r]);
        float oo = sigm(acc[3][r] + xv[3][r]);
        c0[r] = ff * c0[r] + ii * gg;
        h0w[(quad * 4 + r) * H0S + 16 * w + l16] = (f16)(oo * reluf(c0[r]));
      }
      __syncthreads();  // h0w complete
      // ---- phase B: layer1 GEMM. K=256(h0 new)+128(h1 prev). wave w tiles {w, w+16}
      f16x8 afB[8], afU[4];
#pragma unroll
      for (int kf = 0; kf < 8; kf++)
        afB[kf] = *(const f16x8*)&h0w[l16 * H0S + kf * 32 + quad * 8];
#pragma unroll
      for (int kf = 0; kf < 4; kf++)
        afU[kf] = *(const f16x8*)&h1b[l16 * H1S + kf * 32 + quad * 8];
#pragma unroll
      for (int a = 0; a < 2; a++) {
        const int nt = w + 16 * a;
        f32x4 z = {0.f, 0.f, 0.f, 0.f};
#pragma unroll
        for (int kf = 0; kf < 8; kf++)
          z = __builtin_amdgcn_mfma_f32_16x16x32_f16(afB[kf], W1v[(nt * 8 + kf) * 64 + lane], z, 0, 0, 0);
#pragma unroll
        for (int kf = 0; kf < 4; kf++)
          z = __builtin_amdgcn_mfma_f32_16x16x32_f16(afU[kf], U1v[(nt * 4 + kf) * 64 + lane], z, 0, 0, 0);
        const float bc = biasB[nt * 16 + l16];
#pragma unroll
        for (int r = 0; r < 4; r++)
          zb[(quad * 4 + r) * ZS + nt * 16 + l16] = z[r] + bc;
      }
      __syncthreads();  // z ready, afU reads done
      {  // ---- layer1 gates: 16 seqs x 128 units
        const int unit = tid & 127, sq = tid >> 7;
#pragma unroll
        for (int e = 0; e < 2; e++) {
          const int seq = sq + 8 * e;
          float ii = sigm(zb[seq * ZS + unit]);
          float ff = sigm(zb[seq * ZS + 128 + unit]);
          float gg = reluf(zb[seq * ZS + 256 + unit]);
          float oo = sigm(zb[seq * ZS + 384 + unit]);
          c1s[e] = ff * c1s[e] + ii * gg;
          h1b[seq * H1S + unit] = (f16)(oo * reluf(c1s[e]));
        }
      }
      __syncthreads();  // h1 complete, zb free
      // ---- phase C: layer2. K=128(h1 new)+64(h2 prev). wave w tile w
      f16x8 afC[6];
#pragma unroll
      for (int kf = 0; kf < 4; kf++)
        afC[kf] = *(const f16x8*)&h1b[l16 * H1S + kf * 32 + quad * 8];
#pragma unroll
      for (int kf = 0; kf < 2; kf++)
        afC[4 + kf] = *(const f16x8*)&h2b[l16 * H2S + kf * 32 + quad * 8];
      {
        f32x4 z = {0.f, 0.f, 0.f, 0.f};
#pragma unroll
        for (int kf = 0; kf < 4; kf++)
          z = __builtin_amdgcn_mfma_f32_16x16x32_f16(afC[kf], W2v[(w * 4 + kf) * 64 + lane], z, 0, 0, 0);
#pragma unroll
        for (int kf = 0; kf < 2; kf++)
          z = __builtin_amdgcn_mfma_f32_16x16x32_f16(afC[4 + kf], U2v[(w * 2 + kf) * 64 + lane], z, 0, 0, 0);
        const float bc = biasC[w * 16 + l16];
#pragma unroll
        for (int r = 0; r < 4; r++)
          zb[(quad * 4 + r) * ZS + w * 16 + l16] = z[r] + bc;
      }
      __syncthreads();  // z ready, h2 reads done
      {  // ---- layer2 gates: 16 seqs x 64 units
        const int unit = tid & 63, seq = tid >> 6;
        float ii = sigm(zb[seq * ZS + unit]);
        float ff = sigm(zb[seq * ZS + 64 + unit]);
        float gg = reluf(zb[seq * ZS + 128 + unit]);
        float oo = sigm(zb[seq * ZS + 192 + unit]);
        c2 = ff * c2 + ii * gg;
        h2b[seq * H2S + unit] = (f16)(oo * reluf(c2));
      }
      __syncthreads();
    }
    // ---- paragraph dense stack on h2b
    {
      const int j = tid & 127, sq = tid >> 7;
#pragma unroll
      for (int e = 0; e < 2; e++) {
        const int seq = sq + 8 * e;
        float a = A.pd0b[j];
        for (int k = 0; k < 64; k++) a += (float)h2b[seq * H2S + k] * A.pd0W[k * 128 + j];
        zb[seq * ZS + j] = reluf(a);
      }
    }
    __syncthreads();
    {
      const int j = tid & 63, seq = tid >> 6;
      float a = A.pd1b[j];
      for (int k = 0; k < 128; k++) a += zb[seq * ZS + k] * A.pd1W[k * 64 + j];
      zb[seq * ZS + 256 + j] = reluf(a);
    }
    __syncthreads();
    if (tid < 512) {
      const int j = tid & 31, seq = tid >> 5;
      float a = A.pd2b[j];
      for (int k = 0; k < 64; k++) a += zb[seq * ZS + 256 + k] * A.pd2W[k * 32 + j];
      A.feat[(s0 + seq) * 64 + 32 + j] = a;
    }
  } else {
    // ================= title: seqs s0..s0+15, 64 steps =================
    const int s0 = (blk - 8) * 16;
    if (tid < 256) biasC[tid] = A.tl1_b[tid];
    float c0s[2] = {0.f, 0.f};
    float c1 = 0.f;
    const f16* xbase = A.xtW + (size_t)s0 * 64 * 512;
    __syncthreads();

    for (int t = 0; t < 64; t++) {
      // ---- L0: K=128 (h in h1b). wave w tiles {w, w+16}; z includes x (bias folded)
      float xv[2][4];
#pragma unroll
      for (int a = 0; a < 2; a++)
#pragma unroll
        for (int r = 0; r < 4; r++)
          xv[a][r] = (float)xbase[((size_t)(quad * 4 + r) * 64 + t) * 512 + 16 * w + 256 * a + l16];
      f16x8 af[4];
#pragma unroll
      for (int kf = 0; kf < 4; kf++)
        af[kf] = *(const f16x8*)&h1b[l16 * H1S + kf * 32 + quad * 8];
#pragma unroll
      for (int a = 0; a < 2; a++) {
        const int nt = w + 16 * a;
        f32x4 z = {0.f, 0.f, 0.f, 0.f};
#pragma unroll
        for (int kf = 0; kf < 4; kf++)
          z = __builtin_amdgcn_mfma_f32_16x16x32_f16(af[kf], U0tv[(nt * 4 + kf) * 64 + lane], z, 0, 0, 0);
#pragma unroll
        for (int r = 0; r < 4; r++)
          zb[(quad * 4 + r) * ZS + nt * 16 + l16] = z[r] + xv[a][r];
      }
      __syncthreads();
      {  // L0 gates: 16 seqs x 128 units
        const int unit = tid & 127, sq = tid >> 7;
#pragma unroll
        for (int e = 0; e < 2; e++) {
          const int seq = sq + 8 * e;
          float ii = sigm(zb[seq * ZS + unit]);
          float ff = sigm(zb[seq * ZS + 128 + unit]);
          float gg = reluf(zb[seq * ZS + 256 + unit]);
          float oo = sigm(zb[seq * ZS + 384 + unit]);
          c0s[e] = ff * c0s[e] + ii * gg;
          h1b[seq * H1S + unit] = (f16)(oo * reluf(c0s[e]));
        }
      }
      __syncthreads();
      // ---- L1: K=128(h0 new)+64(h1 prev in h2b). wave w tile w
      f16x8 afC[6];
#pragma unroll
      for (int kf = 0; kf < 4; kf++)
        afC[kf] = *(const f16x8*)&h1b[l16 * H1S + kf * 32 + quad * 8];
#pragma unroll
      for (int kf = 0; kf < 2; kf++)
        afC[4 + kf] = *(const f16x8*)&h2b[l16 * H2S + kf * 32 + quad * 8];
      {
        f32x4 z = {0.f, 0.f, 0.f, 0.f};
#pragma unroll
        for (int kf = 0; kf < 4; kf++)
          z = __builtin_amdgcn_mfma_f32_16x16x32_f16(afC[kf], W1tv[(w * 4 + kf) * 64 + lane], z, 0, 0, 0);
#pragma unroll
        for (int kf = 0; kf < 2; kf++)
          z = __builtin_amdgcn_mfma_f32_16x16x32_f16(afC[4 + kf], U1tv[(w * 2 + kf) * 64 + lane], z, 0, 0, 0);
        const float bc = biasC[w * 16 + l16];
#pragma unroll
        for (int r = 0; r < 4; r++)
          zb[(quad * 4 + r) * ZS + w * 16 + l16] = z[r] + bc;
      }
      __syncthreads();
      {  // L1 gates: 16 seqs x 64 units
        const int unit = tid & 63, seq = tid >> 6;
        float ii = sigm(zb[seq * ZS + unit]);
        float ff = sigm(zb[seq * ZS + 64 + unit]);
        float gg = reluf(zb[seq * ZS + 128 + unit]);
        float oo = sigm(zb[seq * ZS + 192 + unit]);
        c1 = ff * c1 + ii * gg;
        h2b[seq * H2S + unit] = (f16)(oo * reluf(c1));
      }
      __syncthreads();
    }
    // ---- title dense stack on h2b
    {
      const int j = tid & 127, sq = tid >> 7;
#pragma unroll
      for (int e = 0; e < 2; e++) {
        const int seq = sq + 8 * e;
        float a = A.td0b[j];
        for (int k = 0; k < 64; k++) a += (float)h2b[seq * H2S + k] * A.td0W[k * 128 + j];
        zb[seq * ZS + j] = reluf(a);
      }
    }
    __syncthreads();
    {
      const int j = tid & 63, seq = tid >> 6;
      float a = A.td1b[j];
      for (int k = 0; k < 128; k++) a += zb[seq * ZS + k] * A.td1W[k * 64 + j];
      zb[seq * ZS + 256 + j] = reluf(a);
    }
    __syncthreads();
    if (tid < 512) {
      const int j = tid & 31, seq = tid >> 5;
      float a = A.td2b[j];
      for (int k = 0; k < 64; k++) a += zb[seq * ZS + 256 + k] * A.td2W[k * 32 + j];
      A.feat[(s0 + seq) * 64 + j] = a;
    }
  }
}

// ---------------- head: mean over N=16, 4 dense layers, sigmoid
__global__ __launch_bounds__(256) void head_kernel(const float* __restrict__ feat,
    const float* __restrict__ L0W, const float* __restrict__ L0b,
    const float* __restrict__ L1W, const float* __restrict__ L1b,
    const float* __restrict__ L2W, const float* __restrict__ L2b,
    const float* __restrict__ L3W, const float* __restrict__ L3b,
    float* __restrict__ out) {
  __shared__ float xb[512];
  __shared__ float y0[2048];
  __shared__ float y1[1024];
  __shared__ float y2[512];
  const int tid = threadIdx.x;
  for (int idx = tid; idx < 512; idx += 256) {
    int b = idx >> 6, d = idx & 63;
    float s = 0.f;
    for (int n = 0; n < 16; n++) s += feat[(b * 16 + n) * 64 + d];
    xb[idx] = s * (1.f / 16.f);
  }
  __syncthreads();
  for (int idx = tid; idx < 2048; idx += 256) {
    int b = idx >> 8, j = idx & 255;
    float a = L0b[j];
    for (int k = 0; k < 64; k++) a += xb[b * 64 + k] * L0W[k * 256 + j];
    y0[idx] = reluf(a);
  }
  __syncthreads();
  for (int idx = tid; idx < 1024; idx += 256) {
    int b = idx >> 7, j = idx & 127;
    float a = L1b[j];
    for (int k = 0; k < 256; k++) a += y0[b * 256 + k] * L1W[k * 128 + j];
    y1[idx] = reluf(a);
  }
  __syncthreads();
  for (int idx = tid; idx < 512; idx += 256) {
    int b = idx >> 6, j = idx & 63;
    float a = L2b[j];
    for (int k = 0; k < 128; k++) a += y1[b * 128 + k] * L2W[k * 64 + j];
    y2[idx] = reluf(a);
  }
  __syncthreads();
  {
    int b = tid >> 5, j = tid & 31;
    float a = L3b[j];
    for (int k = 0; k < 64; k++) a += y2[b * 64 + k] * L3W[k * 32 + j];
    out[b * 32 + j] = 1.f / (1.f + __expf(-a));
  }
}

extern "C" void kernel_launch(void* const* d_in, const int* in_sizes, int n_in,
                              void* d_out, int out_size, void* d_ws, size_t ws_size,
                              hipStream_t stream) {
  const int*   t_tok = (const int*)d_in[0];
  const int*   p_tok = (const int*)d_in[1];
  const float* emb_t = (const float*)d_in[2];
  const float* emb_p = (const float*)d_in[3];
  const float* tl0_W = (const float*)d_in[4];
  const float* tl0_U = (const float*)d_in[5];
  const float* tl0_b = (const float*)d_in[6];
  const float* tl1_W = (const float*)d_in[7];
  const float* tl1_U = (const float*)d_in[8];
  const float* tl1_b = (const float*)d_in[9];
  const float* td0_W = (const float*)d_in[10];
  const float* td0_b = (const float*)d_in[11];
  const float* td1_W = (const float*)d_in[12];
  const float* td1_b = (const float*)d_in[13];
  const float* td2_W = (const float*)d_in[14];
  const float* td2_b = (const float*)d_in[15];
  const float* pl0_W = (const float*)d_in[16];
  const float* pl0_U = (const float*)d_in[17];
  const float* pl0_b = (const float*)d_in[18];
  const float* pl1_W = (const float*)d_in[19];
  const float* pl1_U = (const float*)d_in[20];
  const float* pl1_b = (const float*)d_in[21];
  const float* pl2_W = (const float*)d_in[22];
  const float* pl2_U = (const float*)d_in[23];
  const float* pl2_b = (const float*)d_in[24];
  const float* pd0_W = (const float*)d_in[25];
  const float* pd0_b = (const float*)d_in[26];
  const float* pd1_W = (const float*)d_in[27];
  const float* pd1_b = (const float*)d_in[28];
  const float* pd2_W = (const float*)d_in[29];
  const float* pd2_b = (const float*)d_in[30];
  const float* L0_W  = (const float*)d_in[31];
  const float* L0_b  = (const float*)d_in[32];
  const float* L1_W  = (const float*)d_in[33];
  const float* L1_b  = (const float*)d_in[34];
  const float* L2_W  = (const float*)d_in[35];
  const float* L2_b  = (const float*)d_in[36];
  const float* L3_W  = (const float*)d_in[37];
  const float* L3_b  = (const float*)d_in[38];

  char* ws = (char*)d_ws;
  size_t off = 0;
  auto alloc = [&](size_t bytes) {
    void* ptr = ws + off;
    off += (bytes + 255) & ~(size_t)255;
    return ptr;
  };
  f16* xpW = (f16*)alloc((size_t)65536 * 1024 * 2);
  f16* xtW = (f16*)alloc((size_t)8192 * 512 * 2);
  f16* Bp  = (f16*)alloc((size_t)256 * 1024 * 2);
  f16* Bt  = (f16*)alloc((size_t)128 * 512 * 2);
  f16* U0f = (f16*)alloc((size_t)256 * 1024 * 2);
  f16* W1f = (f16*)alloc((size_t)256 * 512 * 2);
  f16* U1f = (f16*)alloc((size_t)128 * 512 * 2);
  f16* W2f = (f16*)alloc((size_t)128 * 256 * 2);
  f16* U2f = (f16*)alloc((size_t)64 * 256 * 2);
  f16* U0tf = (f16*)alloc((size_t)128 * 512 * 2);
  f16* W1tf = (f16*)alloc((size_t)128 * 256 * 2);
  f16* U1tf = (f16*)alloc((size_t)64 * 256 * 2);
  float* feat = (float*)alloc((size_t)128 * 64 * 4);

  // pack all B operands into MFMA b-frag layout
  pack_bsw<8><<<1024, 256, 0, stream>>>(pl0_W, Bp, 1024);
  pack_bsw<4><<<256, 256, 0, stream>>>(tl0_W, Bt, 512);
  pack_bsw<8><<<1024, 256, 0, stream>>>(pl0_U, U0f, 1024);
  pack_bsw<8><<<512, 256, 0, stream>>>(pl1_W, W1f, 512);
  pack_bsw<4><<<256, 256, 0, stream>>>(pl1_U, U1f, 512);
  pack_bsw<4><<<128, 256, 0, stream>>>(pl2_W, W2f, 256);
  pack_bsw<2><<<64, 256, 0, stream>>>(pl2_U, U2f, 256);
  pack_bsw<4><<<256, 256, 0, stream>>>(tl0_U, U0tf, 512);
  pack_bsw<4><<<128, 256, 0, stream>>>(tl1_W, W1tf, 256);
  pack_bsw<2><<<64, 256, 0, stream>>>(tl1_U, U1tf, 256);
  // xW + b precompute
  gemm_xw<256, 8, 1024, 64><<<1024, 256, 0, stream>>>(p_tok, emb_p, Bp, pl0_b, xpW);
  gemm_xw<128, 4, 512, 32><<<128, 256, 0, stream>>>(t_tok, emb_t, Bt, tl0_b, xtW);

  RArgs ra;
  ra.xpW = xpW; ra.xtW = xtW;
  ra.U0f = U0f; ra.W1f = W1f; ra.U1f = U1f; ra.W2f = W2f; ra.U2f = U2f;
  ra.U0tf = U0tf; ra.W1tf = W1tf; ra.U1tf = U1tf;
  ra.pl1_b = pl1_b; ra.pl2_b = pl2_b; ra.tl1_b = tl1_b;
  ra.pd0W = pd0_W; ra.pd0b = pd0_b; ra.pd1W = pd1_W; ra.pd1b = pd1_b;
  ra.pd2W = pd2_W; ra.pd2b = pd2_b;
  ra.td0W = td0_W; ra.td0b = td0_b; ra.td1W = td1_W; ra.td1b = td1_b;
  ra.td2W = td2_W; ra.td2b = td2_b;
  ra.feat = feat;
  recur2<<<16, 1024, 0, stream>>>(ra);

  head_kernel<<<1, 256, 0, stream>>>(feat, L0_W, L0_b, L1_W, L1_b, L2_W, L2_b,
                                     L3_W, L3_b, (float*)d_out);
}

// Round 3
// 8107.381 us; speedup vs baseline: 1.0375x; 1.0375x over previous
//
#include <hip/hip_runtime.h>
#include <hip/hip_fp16.h>

typedef _Float16 f16;
typedef _Float16 f16x8 __attribute__((ext_vector_type(8)));
typedef float    f32x4 __attribute__((ext_vector_type(4)));
typedef unsigned short ushort;

__device__ __forceinline__ float sigm(float x) { return 1.f / (1.f + __expf(-x)); }
__device__ __forceinline__ float reluf(float x) { return x > 0.f ? x : 0.f; }
__device__ __forceinline__ float h2f(ushort u) { return (float)__builtin_bit_cast(f16, u); }

// ---------------- pack B for MFMA b-frag layout (validated R1/R2)
// dst[((c*KF+kf)*64+L)*8+j] = B[kf*32 + (L>>4)*8 + j][c*16 + (L&15)]
template <int KF>
__global__ void pack_bsw(const float* __restrict__ B, f16* __restrict__ dst, int N) {
  int id = blockIdx.x * 256 + threadIdx.x;
  int total = KF * 32 * N;
  if (id >= total) return;
  int j  = id & 7;
  int L  = (id >> 3) & 63;
  int r  = id >> 9;
  int kf = r & (KF - 1);
  int c  = r / KF;
  int k  = kf * 32 + ((L >> 4) * 8) + j;
  int n  = c * 16 + (L & 15);
  dst[id] = (f16)B[k * N + n];
}

// ---------------- xW GEMM (validated R1/R2): C[M][N] = gather(emb,tok)@B + bias, f16
template <int K, int KF, int N, int NC>
__global__ __launch_bounds__(256) void gemm_xw(const int* __restrict__ tok,
                                               const float* __restrict__ emb,
                                               const f16* __restrict__ Bsw,
                                               const float* __restrict__ bias,
                                               f16* __restrict__ C) {
  __shared__ int tokLds[64];
  __shared__ f16x8 bLds[8 * 64];
  const int tid = threadIdx.x;
  const int blk = blockIdx.x;
  if (tid < 64) tokLds[tid] = tok[blk * 64 + tid];
  __syncthreads();
  const int wave = tid >> 6, lane = tid & 63;
  const int quad = lane >> 4, l16 = lane & 15;
  const int m0 = wave * 16;

  f16x8 a[KF];
  {
    const int row = m0 + l16;
    const float* arow = emb + (long)tokLds[row] * K + quad * 8;
#pragma unroll
    for (int kf = 0; kf < KF; kf++) {
      float4 v0 = *(const float4*)(arow + kf * 32);
      float4 v1 = *(const float4*)(arow + kf * 32 + 4);
      f16x8 tv;
      tv[0] = (f16)v0.x; tv[1] = (f16)v0.y; tv[2] = (f16)v0.z; tv[3] = (f16)v0.w;
      tv[4] = (f16)v1.x; tv[5] = (f16)v1.y; tv[6] = (f16)v1.z; tv[7] = (f16)v1.w;
      a[kf] = tv;
    }
  }
  const long crow = (long)(blk * 64 + m0) * N;
  const f16x8* Bfrag = (const f16x8*)Bsw;
  for (int c = 0; c < NC; c++) {
    for (int i = tid; i < KF * 64; i += 256) bLds[i] = Bfrag[c * KF * 64 + i];
    __syncthreads();
    f32x4 acc = {0.f, 0.f, 0.f, 0.f};
#pragma unroll
    for (int kf = 0; kf < KF; kf++)
      acc = __builtin_amdgcn_mfma_f32_16x16x32_f16(a[kf], bLds[kf * 64 + lane], acc, 0, 0, 0);
    const int col = c * 16 + l16;
    const float bc = bias[col];
#pragma unroll
    for (int r = 0; r < 4; r++)
      C[crow + (long)(quad * 4 + r) * N + col] = (f16)(acc[r] + bc);
    __syncthreads();
  }
}

// ---------------- MFMA recurrence v3: 512 thr (8 waves), in-register gates
struct RArgs {
  const f16 *xpW, *xtW;
  const f16 *U0f, *W1f, *U1f, *W2f, *U2f;
  const f16 *U0tf, *W1tf, *U1tf;
  const float *pl1_b, *pl2_b, *tl1_b;
  const float *pd0W, *pd0b, *pd1W, *pd1b, *pd2W, *pd2b;
  const float *td0W, *td0b, *td1W, *td1b, *td2W, *td2b;
  float* feat;
};

#define H0S 264
#define H1S 136
#define H2S 72

__global__ __launch_bounds__(512, 2) void recur3(RArgs A) {
  __shared__ f16 h0b[2][16 * H0S];
  __shared__ f16 h1b[2][16 * H1S];
  __shared__ f16 h2b[2][16 * H2S];
  __shared__ float zm[3200];
  const int tid = threadIdx.x;
  const int w = tid >> 6, lane = tid & 63;
  const int quad = lane >> 4, l16 = lane & 15;
  const int blk = blockIdx.x;

  for (int i = tid; i < 2 * 16 * H0S; i += 512) ((f16*)h0b)[i] = (f16)0.f;
  for (int i = tid; i < 2 * 16 * H1S; i += 512) ((f16*)h1b)[i] = (f16)0.f;
  for (int i = tid; i < 2 * 16 * H2S; i += 512) ((f16*)h2b)[i] = (f16)0.f;

  const f16x8* U0v  = (const f16x8*)A.U0f;
  const f16x8* W1v  = (const f16x8*)A.W1f;
  const f16x8* U1v  = (const f16x8*)A.U1f;
  const f16x8* W2v  = (const f16x8*)A.W2f;
  const f16x8* U2v  = (const f16x8*)A.U2f;
  const f16x8* U0tv = (const f16x8*)A.U0tf;
  const f16x8* W1tv = (const f16x8*)A.W1tf;
  const f16x8* U1tv = (const f16x8*)A.U1tf;

  if (blk < 8) {
    // ============== paragraph: 16 seqs, 512 steps, 3 layers ==============
    const int s0 = blk * 16;
    float b1r[4], b2r[4];
#pragma unroll
    for (int g = 0; g < 4; g++) b1r[g] = A.pl1_b[16 * (w + 8 * g) + l16];
    if (w < 4) {
#pragma unroll
      for (int g = 0; g < 4; g++) b2r[g] = A.pl2_b[16 * (w + 4 * g) + l16];
    }
    float c0[2][4] = {}, c1[4] = {}, c2[4] = {};
    const char* xb = (const char*)A.xpW;
    unsigned int xoff[4];
#pragma unroll
    for (int r = 0; r < 4; r++)
      xoff[r] = (unsigned int)((s0 + quad * 4 + r) * 512) * 2048u + 32u * w + 2u * l16;
    __syncthreads();

    for (int t = 0; t < 512; t++) {
      const f16* h0r = h0b[t & 1];
      f16*       h0w = h0b[(t + 1) & 1];
      const f16* h1r = h1b[t & 1];
      f16*       h1w = h1b[(t + 1) & 1];
      const f16* h2r = h2b[t & 1];
      f16*       h2w = h2b[(t + 1) & 1];
      // x loads for this step (overlap with phase-A GEMM); col bytes: 32w+256e+512g+2*l16
      ushort xv[2][4][4];
#pragma unroll
      for (int e = 0; e < 2; e++)
#pragma unroll
        for (int g = 0; g < 4; g++)
#pragma unroll
          for (int r = 0; r < 4; r++)
            xv[e][g][r] = *(const ushort*)(xb + xoff[r] + e * 256 + g * 512);
#pragma unroll
      for (int r = 0; r < 4; r++) xoff[r] += 2048u;
      // ---- phase A: layer0 GEMM + in-register gates
      f16x8 af[8];
#pragma unroll
      for (int kf = 0; kf < 8; kf++)
        af[kf] = *(const f16x8*)&h0r[l16 * H0S + kf * 32 + quad * 8];
#pragma unroll
      for (int e = 0; e < 2; e++) {
        const int ut = w + 8 * e;
        f32x4 zz[4];
#pragma unroll
        for (int g = 0; g < 4; g++) {
          const int ct = ut + 16 * g;
          f16x8 bfr[8];
#pragma unroll
          for (int kf = 0; kf < 8; kf++) bfr[kf] = U0v[(ct * 8 + kf) * 64 + lane];
          f32x4 z = {0.f, 0.f, 0.f, 0.f};
#pragma unroll
          for (int kf = 0; kf < 8; kf++)
            z = __builtin_amdgcn_mfma_f32_16x16x32_f16(af[kf], bfr[kf], z, 0, 0, 0);
          zz[g] = z;
        }
#pragma unroll
        for (int r = 0; r < 4; r++) {
          float ii = sigm(zz[0][r] + h2f(xv[e][0][r]));
          float ff = sigm(zz[1][r] + h2f(xv[e][1][r]));
          float gg = reluf(zz[2][r] + h2f(xv[e][2][r]));
          float oo = sigm(zz[3][r] + h2f(xv[e][3][r]));
          c0[e][r] = ff * c0[e][r] + ii * gg;
          h0w[(quad * 4 + r) * H0S + 16 * ut + l16] = (f16)(oo * reluf(c0[e][r]));
        }
      }
      __syncthreads();
      // ---- phase B: layer1 (K=256 new h0 + 128 prev h1), wave w -> unit-tile w
      {
        f16x8 afB[8], afU[4];
#pragma unroll
        for (int kf = 0; kf < 8; kf++)
          afB[kf] = *(const f16x8*)&h0w[l16 * H0S + kf * 32 + quad * 8];
#pragma unroll
        for (int kf = 0; kf < 4; kf++)
          afU[kf] = *(const f16x8*)&h1r[l16 * H1S + kf * 32 + quad * 8];
        f32x4 zz[4];
#pragma unroll
        for (int g = 0; g < 4; g++) {
          const int ct = w + 8 * g;
          f16x8 bfr[12];
#pragma unroll
          for (int kf = 0; kf < 8; kf++) bfr[kf] = W1v[(ct * 8 + kf) * 64 + lane];
#pragma unroll
          for (int kf = 0; kf < 4; kf++) bfr[8 + kf] = U1v[(ct * 4 + kf) * 64 + lane];
          f32x4 z = {0.f, 0.f, 0.f, 0.f};
#pragma unroll
          for (int kf = 0; kf < 8; kf++)
            z = __builtin_amdgcn_mfma_f32_16x16x32_f16(afB[kf], bfr[kf], z, 0, 0, 0);
#pragma unroll
          for (int kf = 0; kf < 4; kf++)
            z = __builtin_amdgcn_mfma_f32_16x16x32_f16(afU[kf], bfr[8 + kf], z, 0, 0, 0);
          zz[g] = z;
        }
#pragma unroll
        for (int r = 0; r < 4; r++) {
          float ii = sigm(zz[0][r] + b1r[0]);
          float ff = sigm(zz[1][r] + b1r[1]);
          float gg = reluf(zz[2][r] + b1r[2]);
          float oo = sigm(zz[3][r] + b1r[3]);
          c1[r] = ff * c1[r] + ii * gg;
          h1w[(quad * 4 + r) * H1S + 16 * w + l16] = (f16)(oo * reluf(c1[r]));
        }
      }
      __syncthreads();
      // ---- phase C: layer2 (K=128 new h1 + 64 prev h2), waves 0..3
      if (w < 4) {
        f16x8 afC[6];
#pragma unroll
        for (int kf = 0; kf < 4; kf++)
          afC[kf] = *(const f16x8*)&h1w[l16 * H1S + kf * 32 + quad * 8];
#pragma unroll
        for (int kf = 0; kf < 2; kf++)
          afC[4 + kf] = *(const f16x8*)&h2r[l16 * H2S + kf * 32 + quad * 8];
        f32x4 zz[4];
#pragma unroll
        for (int g = 0; g < 4; g++) {
          const int ct = w + 4 * g;
          f16x8 bfr[6];
#pragma unroll
          for (int kf = 0; kf < 4; kf++) bfr[kf] = W2v[(ct * 4 + kf) * 64 + lane];
#pragma unroll
          for (int kf = 0; kf < 2; kf++) bfr[4 + kf] = U2v[(ct * 2 + kf) * 64 + lane];
          f32x4 z = {0.f, 0.f, 0.f, 0.f};
#pragma unroll
          for (int kf = 0; kf < 6; kf++)
            z = __builtin_amdgcn_mfma_f32_16x16x32_f16(afC[kf], bfr[kf], z, 0, 0, 0);
          zz[g] = z;
        }
#pragma unroll
        for (int r = 0; r < 4; r++) {
          float ii = sigm(zz[0][r] + b2r[0]);
          float ff = sigm(zz[1][r] + b2r[1]);
          float gg = reluf(zz[2][r] + b2r[2]);
          float oo = sigm(zz[3][r] + b2r[3]);
          c2[r] = ff * c2[r] + ii * gg;
          h2w[(quad * 4 + r) * H2S + 16 * w + l16] = (f16)(oo * reluf(c2[r]));
        }
      }
      __syncthreads();
    }
    // ---- paragraph dense stack; final h2 is h2b[0] ((511+1)&1)
    const f16* hf = h2b[0];
#pragma unroll
    for (int e = 0; e < 4; e++) {
      const int idx = tid + 512 * e, sq = idx >> 7, j = idx & 127;
      float a = A.pd0b[j];
      for (int k = 0; k < 64; k++) a += (float)hf[sq * H2S + k] * A.pd0W[k * 128 + j];
      zm[sq * 136 + j] = reluf(a);
    }
    __syncthreads();
#pragma unroll
    for (int e = 0; e < 2; e++) {
      const int idx = tid + 512 * e, sq = idx >> 6, j = idx & 63;
      float a = A.pd1b[j];
      for (int k = 0; k < 128; k++) a += zm[sq * 136 + k] * A.pd1W[k * 64 + j];
      zm[2176 + sq * 64 + j] = reluf(a);
    }
    __syncthreads();
    {
      const int sq = tid >> 5, j = tid & 31;
      float a = A.pd2b[j];
      for (int k = 0; k < 64; k++) a += zm[2176 + sq * 64 + k] * A.pd2W[k * 32 + j];
      A.feat[(s0 + sq) * 64 + 32 + j] = a;
    }
  } else {
    // ============== title: 16 seqs, 64 steps, 2 layers ==============
    const int s0 = (blk - 8) * 16;
    float bt[4];
    if (w < 4) {
#pragma unroll
      for (int g = 0; g < 4; g++) bt[g] = A.tl1_b[16 * (w + 4 * g) + l16];
    }
    float c0t[4] = {}, c1t[4] = {};
    const char* xb = (const char*)A.xtW;
    unsigned int xoff[4];
#pragma unroll
    for (int r = 0; r < 4; r++)
      xoff[r] = (unsigned int)((s0 + quad * 4 + r) * 64) * 1024u + 32u * w + 2u * l16;
    __syncthreads();

    for (int t = 0; t < 64; t++) {
      const f16* h0r = h1b[t & 1];
      f16*       h0w = h1b[(t + 1) & 1];
      const f16* h1r = h2b[t & 1];
      f16*       h1w = h2b[(t + 1) & 1];
      ushort xv[4][4];
#pragma unroll
      for (int g = 0; g < 4; g++)
#pragma unroll
        for (int r = 0; r < 4; r++)
          xv[g][r] = *(const ushort*)(xb + xoff[r] + g * 256);
#pragma unroll
      for (int r = 0; r < 4; r++) xoff[r] += 1024u;
      // ---- L0: K=128 prev h0; wave w -> unit-tile w (col-tiles w+8g)
      {
        f16x8 af[4];
#pragma unroll
        for (int kf = 0; kf < 4; kf++)
          af[kf] = *(const f16x8*)&h0r[l16 * H1S + kf * 32 + quad * 8];
        f32x4 zz[4];
#pragma unroll
        for (int g = 0; g < 4; g++) {
          const int ct = w + 8 * g;
          f16x8 bfr[4];
#pragma unroll
          for (int kf = 0; kf < 4; kf++) bfr[kf] = U0tv[(ct * 4 + kf) * 64 + lane];
          f32x4 z = {0.f, 0.f, 0.f, 0.f};
#pragma unroll
          for (int kf = 0; kf < 4; kf++)
            z = __builtin_amdgcn_mfma_f32_16x16x32_f16(af[kf], bfr[kf], z, 0, 0, 0);
          zz[g] = z;
        }
#pragma unroll
        for (int r = 0; r < 4; r++) {
          float ii = sigm(zz[0][r] + h2f(xv[0][r]));
          float ff = sigm(zz[1][r] + h2f(xv[1][r]));
          float gg = reluf(zz[2][r] + h2f(xv[2][r]));
          float oo = sigm(zz[3][r] + h2f(xv[3][r]));
          c0t[r] = ff * c0t[r] + ii * gg;
          h0w[(quad * 4 + r) * H1S + 16 * w + l16] = (f16)(oo * reluf(c0t[r]));
        }
      }
      __syncthreads();
      // ---- L1: K=128 new h0 + 64 prev h1; waves 0..3
      if (w < 4) {
        f16x8 afC[6];
#pragma unroll
        for (int kf = 0; kf < 4; kf++)
          afC[kf] = *(const f16x8*)&h0w[l16 * H1S + kf * 32 + quad * 8];
#pragma unroll
        for (int kf = 0; kf < 2; kf++)
          afC[4 + kf] = *(const f16x8*)&h1r[l16 * H2S + kf * 32 + quad * 8];
        f32x4 zz[4];
#pragma unroll
        for (int g = 0; g < 4; g++) {
          const int ct = w + 4 * g;
          f16x8 bfr[6];
#pragma unroll
          for (int kf = 0; kf < 4; kf++) bfr[kf] = W1tv[(ct * 4 + kf) * 64 + lane];
#pragma unroll
          for (int kf = 0; kf < 2; kf++) bfr[4 + kf] = U1tv[(ct * 2 + kf) * 64 + lane];
          f32x4 z = {0.f, 0.f, 0.f, 0.f};
#pragma unroll
          for (int kf = 0; kf < 6; kf++)
            z = __builtin_amdgcn_mfma_f32_16x16x32_f16(afC[kf], bfr[kf], z, 0, 0, 0);
          zz[g] = z;
        }
#pragma unroll
        for (int r = 0; r < 4; r++) {
          float ii = sigm(zz[0][r] + bt[0]);
          float ff = sigm(zz[1][r] + bt[1]);
          float gg = reluf(zz[2][r] + bt[2]);
          float oo = sigm(zz[3][r] + bt[3]);
          c1t[r] = ff * c1t[r] + ii * gg;
          h1w[(quad * 4 + r) * H2S + 16 * w + l16] = (f16)(oo * reluf(c1t[r]));
        }
      }
      __syncthreads();
    }
    // ---- title dense stack; final h1 is h2b[0]
    const f16* hf = h2b[0];
#pragma unroll
    for (int e = 0; e < 4; e++) {
      const int idx = tid + 512 * e, sq = idx >> 7, j = idx & 127;
      float a = A.td0b[j];
      for (int k = 0; k < 64; k++) a += (float)hf[sq * H2S + k] * A.td0W[k * 128 + j];
      zm[sq * 136 + j] = reluf(a);
    }
    __syncthreads();
#pragma unroll
    for (int e = 0; e < 2; e++) {
      const int idx = tid + 512 * e, sq = idx >> 6, j = idx & 63;
      float a = A.td1b[j];
      for (int k = 0; k < 128; k++) a += zm[sq * 136 + k] * A.td1W[k * 64 + j];
      zm[2176 + sq * 64 + j] = reluf(a);
    }
    __syncthreads();
    {
      const int sq = tid >> 5, j = tid & 31;
      float a = A.td2b[j];
      for (int k = 0; k < 64; k++) a += zm[2176 + sq * 64 + k] * A.td2W[k * 32 + j];
      A.feat[(s0 + sq) * 64 + j] = a;
    }
  }
}

// ---------------- head: mean over 16, 4 dense layers, sigmoid
__global__ __launch_bounds__(256) void head_kernel(const float* __restrict__ feat,
    const float* __restrict__ L0W, const float* __restrict__ L0b,
    const float* __restrict__ L1W, const float* __restrict__ L1b,
    const float* __restrict__ L2W, const float* __restrict__ L2b,
    const float* __restrict__ L3W, const float* __restrict__ L3b,
    float* __restrict__ out) {
  __shared__ float xb[512];
  __shared__ float y0[2048];
  __shared__ float y1[1024];
  __shared__ float y2[512];
  const int tid = threadIdx.x;
  for (int idx = tid; idx < 512; idx += 256) {
    int b = idx >> 6, d = idx & 63;
    float s = 0.f;
    for (int n = 0; n < 16; n++) s += feat[(b * 16 + n) * 64 + d];
    xb[idx] = s * (1.f / 16.f);
  }
  __syncthreads();
  for (int idx = tid; idx < 2048; idx += 256) {
    int b = idx >> 8, j = idx & 255;
    float a = L0b[j];
    for (int k = 0; k < 64; k++) a += xb[b * 64 + k] * L0W[k * 256 + j];
    y0[idx] = reluf(a);
  }
  __syncthreads();
  for (int idx = tid; idx < 1024; idx += 256) {
    int b = idx >> 7, j = idx & 127;
    float a = L1b[j];
    for (int k = 0; k < 256; k++) a += y0[b * 256 + k] * L1W[k * 128 + j];
    y1[idx] = reluf(a);
  }
  __syncthreads();
  for (int idx = tid; idx < 512; idx += 256) {
    int b = idx >> 6, j = idx & 63;
    float a = L2b[j];
    for (int k = 0; k < 128; k++) a += y1[b * 128 + k] * L2W[k * 64 + j];
    y2[idx] = reluf(a);
  }
  __syncthreads();
  {
    int b = tid >> 5, j = tid & 31;
    float a = L3b[j];
    for (int k = 0; k < 64; k++) a += y2[b * 64 + k] * L3W[k * 32 + j];
    out[b * 32 + j] = 1.f / (1.f + __expf(-a));
  }
}

extern "C" void kernel_launch(void* const* d_in, const int* in_sizes, int n_in,
                              void* d_out, int out_size, void* d_ws, size_t ws_size,
                              hipStream_t stream) {
  const int*   t_tok = (const int*)d_in[0];
  const int*   p_tok = (const int*)d_in[1];
  const float* emb_t = (const float*)d_in[2];
  const float* emb_p = (const float*)d_in[3];
  const float* tl0_W = (const float*)d_in[4];
  const float* tl0_U = (const float*)d_in[5];
  const float* tl0_b = (const float*)d_in[6];
  const float* tl1_W = (const float*)d_in[7];
  const float* tl1_U = (const float*)d_in[8];
  const float* tl1_b = (const float*)d_in[9];
  const float* td0_W = (const float*)d_in[10];
  const float* td0_b = (const float*)d_in[11];
  const float* td1_W = (const float*)d_in[12];
  const float* td1_b = (const float*)d_in[13];
  const float* td2_W = (const float*)d_in[14];
  const float* td2_b = (const float*)d_in[15];
  const float* pl0_W = (const float*)d_in[16];
  const float* pl0_U = (const float*)d_in[17];
  const float* pl0_b = (const float*)d_in[18];
  const float* pl1_W = (const float*)d_in[19];
  const float* pl1_U = (const float*)d_in[20];
  const float* pl1_b = (const float*)d_in[21];
  const float* pl2_W = (const float*)d_in[22];
  const float* pl2_U = (const float*)d_in[23];
  const float* pl2_b = (const float*)d_in[24];
  const float* pd0_W = (const float*)d_in[25];
  const float* pd0_b = (const float*)d_in[26];
  const float* pd1_W = (const float*)d_in[27];
  const float* pd1_b = (const float*)d_in[28];
  const float* pd2_W = (const float*)d_in[29];
  const float* pd2_b = (const float*)d_in[30];
  const float* L0_W  = (const float*)d_in[31];
  const float* L0_b  = (const float*)d_in[32];
  const float* L1_W  = (const float*)d_in[33];
  const float* L1_b  = (const float*)d_in[34];
  const float* L2_W  = (const float*)d_in[35];
  const float* L2_b  = (const float*)d_in[36];
  const float* L3_W  = (const float*)d_in[37];
  const float* L3_b  = (const float*)d_in[38];

  char* ws = (char*)d_ws;
  size_t off = 0;
  auto alloc = [&](size_t bytes) {
    void* ptr = ws + off;
    off += (bytes + 255) & ~(size_t)255;
    return ptr;
  };
  f16* xpW = (f16*)alloc((size_t)65536 * 1024 * 2);
  f16* xtW = (f16*)alloc((size_t)8192 * 512 * 2);
  f16* Bp  = (f16*)alloc((size_t)256 * 1024 * 2);
  f16* Bt  = (f16*)alloc((size_t)128 * 512 * 2);
  f16* U0f = (f16*)alloc((size_t)256 * 1024 * 2);
  f16* W1f = (f16*)alloc((size_t)256 * 512 * 2);
  f16* U1f = (f16*)alloc((size_t)128 * 512 * 2);
  f16* W2f = (f16*)alloc((size_t)128 * 256 * 2);
  f16* U2f = (f16*)alloc((size_t)64 * 256 * 2);
  f16* U0tf = (f16*)alloc((size_t)128 * 512 * 2);
  f16* W1tf = (f16*)alloc((size_t)128 * 256 * 2);
  f16* U1tf = (f16*)alloc((size_t)64 * 256 * 2);
  float* feat = (float*)alloc((size_t)128 * 64 * 4);

  pack_bsw<8><<<1024, 256, 0, stream>>>(pl0_W, Bp, 1024);
  pack_bsw<4><<<256, 256, 0, stream>>>(tl0_W, Bt, 512);
  pack_bsw<8><<<1024, 256, 0, stream>>>(pl0_U, U0f, 1024);
  pack_bsw<8><<<512, 256, 0, stream>>>(pl1_W, W1f, 512);
  pack_bsw<4><<<256, 256, 0, stream>>>(pl1_U, U1f, 512);
  pack_bsw<4><<<128, 256, 0, stream>>>(pl2_W, W2f, 256);
  pack_bsw<2><<<64, 256, 0, stream>>>(pl2_U, U2f, 256);
  pack_bsw<4><<<256, 256, 0, stream>>>(tl0_U, U0tf, 512);
  pack_bsw<4><<<128, 256, 0, stream>>>(tl1_W, W1tf, 256);
  pack_bsw<2><<<64, 256, 0, stream>>>(tl1_U, U1tf, 256);
  gemm_xw<256, 8, 1024, 64><<<1024, 256, 0, stream>>>(p_tok, emb_p, Bp, pl0_b, xpW);
  gemm_xw<128, 4, 512, 32><<<128, 256, 0, stream>>>(t_tok, emb_t, Bt, tl0_b, xtW);

  RArgs ra;
  ra.xpW = xpW; ra.xtW = xtW;
  ra.U0f = U0f; ra.W1f = W1f; ra.U1f = U1f; ra.W2f = W2f; ra.U2f = U2f;
  ra.U0tf = U0tf; ra.W1tf = W1tf; ra.U1tf = U1tf;
  ra.pl1_b = pl1_b; ra.pl2_b = pl2_b; ra.tl1_b = tl1_b;
  ra.pd0W = pd0_W; ra.pd0b = pd0_b; ra.pd1W = pd1_W; ra.pd1b = pd1_b;
  ra.pd2W = pd2_W; ra.pd2b = pd2_b;
  ra.td0W = td0_W; ra.td0b = td0_b; ra.td1W = td1_W; ra.td1b = td1_b;
  ra.td2W = td2_W; ra.td2b = td2_b;
  ra.feat = feat;
  recur3<<<16, 512, 0, stream>>>(ra);

  head_kernel<<<1, 256, 0, stream>>>(feat, L0_W, L0_b, L1_W, L1_b, L2_W, L2_b,
                                     L3_W, L3_b, (float*)d_out);
}